// Round 13
// baseline (221.393 us; speedup 1.0000x reference)
//
#include <hip/hip_runtime.h>

#define DEV __device__ __forceinline__

typedef __attribute__((ext_vector_type(4))) float f32x4;
typedef __attribute__((ext_vector_type(16))) float f32x16;
typedef __attribute__((ext_vector_type(8))) short bf16x8;

// round-to-nearest-even f32 -> bf16 (bits in a short)
DEV short f2bf(float f) {
    union { float f; unsigned u; } v; v.f = f;
    unsigned r = (v.u + 0x7fffu + ((v.u >> 16) & 1u)) >> 16;
    return (short)r;
}

#ifndef __has_builtin
#define __has_builtin(x) 0
#endif
#if __has_builtin(__builtin_amdgcn_cvt_pk_bf16_f32)
DEV unsigned pkbf(float a, float b) {
    auto r = __builtin_amdgcn_cvt_pk_bf16_f32(a, b);
    union { __typeof__(r) v; unsigned u; } u; u.v = r; return u.u;
}
#else
DEV unsigned pkbf(float a, float b) {
    return (unsigned)(unsigned short)f2bf(a) | ((unsigned)(unsigned short)f2bf(b) << 16);
}
#endif

// async global->LDS, 16 bytes per lane. LDS dest = wave-uniform base + lane*16.
DEV void gl_lds16(const void* g, void* l) {
    __builtin_amdgcn_global_load_lds(
        (__attribute__((address_space(1))) void*)(g),
        (__attribute__((address_space(3))) void*)(l), 16, 0, 0);
}

// Stage ITERS*32 rows x 64 bf16 cols from row-major global (stride ldg shorts)
// into LDS tile with row stride 64 shorts. 16B chunks XOR-swizzled.
template <int ITERS>
DEV void stage_tile(const short* g, int ldg, short* lds, int t) {
    const int w = t >> 6;
#pragma unroll
    for (int it = 0; it < ITERS; ++it) {
        int row = it * 32 + (t >> 3);
        int cx = (t & 7) ^ ((t >> 3) & 7);
        gl_lds16(g + row * ldg + cx * 8, (char*)lds + it * 4096 + (w << 10));
    }
}

// read 8-bf16 fragment: chunk kc (0..7) of tile row r (row stride 64 shorts)
DEV bf16x8 ldfrag(const short* lds, int r, int kc) {
    return *(const bf16x8*)(lds + r * 64 + ((kc ^ (r & 7)) << 3));
}

// ---------------- conversion (all 5 tensors in one launch) ----------------
__global__ void cvt_all(const float* __restrict__ x,
                        const float* __restrict__ wq, const float* __restrict__ wk,
                        const float* __restrict__ wv, const float* __restrict__ wo,
                        short* __restrict__ xb,
                        short* __restrict__ wqb, short* __restrict__ wkb,
                        short* __restrict__ wvb, short* __restrict__ wob) {
    int b = blockIdx.x;
    const float* s; short* d; int i;
    if (b < 6144) {
        s = x; d = xb; i = b * 256 + threadIdx.x;
    } else {
        int r = b - 6144;
        int wi = r / 576, rem = r - wi * 576;
        s = (wi == 0) ? wq : (wi == 1) ? wk : (wi == 2) ? wv : wo;
        d = (wi == 0) ? wqb : (wi == 1) ? wkb : (wi == 2) ? wvb : wob;
        i = rem * 256 + threadIdx.x;
    }
    float4 v = ((const float4*)s)[i];
    short4 o;
    o.x = f2bf(v.x); o.y = f2bf(v.y); o.z = f2bf(v.z); o.w = f2bf(v.w);
    ((short4*)d)[i] = o;
}

// ---------------- fused QKV projection (32x32x16 MFMA, z-fused, 64-row) ------
// One block = 64-row x 64-col tile for ALL THREE outputs; grid 1536 for
// latency hiding (proj is latency-bound: VALUBusy ~10%). Q gets (1/8)*log2(e)
// folded. V^T stored with token columns PERMUTED within each 64-group:
// n = (j&32)|((j&12)<<1)|((j&16)>>2)|(j&3) — matches flash's PV k-slot map.
#define TSTRIDE 136
__global__ __launch_bounds__(256, 4) void proj_gemm(
    const short* __restrict__ xb,
    const short* __restrict__ wq, const short* __restrict__ wk, const short* __restrict__ wv,
    short* __restrict__ Qg, short* __restrict__ Kg, short* __restrict__ Vtg)
{
    __shared__ __align__(16) char smem[32768];
    short* const At = (short*)smem;                 // 64x64 = 8 KB
    short* const Bq = (short*)(smem + 8192);
    short* const Bk = (short*)(smem + 16384);
    short* const Bv = (short*)(smem + 24576);
    short* const Ct = (short*)smem;                 // epilogue overlay (17.4 KB)
    const int t = threadIdx.x;
    const int row0 = blockIdx.x * 64, col0 = blockIdx.y * 64;
    const int lane = t & 63, w = t >> 6;
    const int l31 = lane & 31, lh = lane >> 5;
    const int wm = w >> 1, wn = w & 1;   // wave tile: rows wm*32, cols wn*32

    f32x16 acc[3];
#pragma unroll
    for (int z = 0; z < 3; ++z) acc[z] = (f32x16)(0.f);

    const short* Asrc = xb + (size_t)row0 * 768;
    const short* Qs = wq + (size_t)col0 * 768;
    const short* Ks = wk + (size_t)col0 * 768;
    const short* Vs = wv + (size_t)col0 * 768;

    for (int k = 0; k < 12; ++k) {
        __syncthreads();
        stage_tile<2>(Asrc + k * 64, 768, At, t);
        stage_tile<2>(Qs + k * 64, 768, Bq, t);
        stage_tile<2>(Ks + k * 64, 768, Bk, t);
        stage_tile<2>(Vs + k * 64, 768, Bv, t);
        __syncthreads();
#pragma unroll
        for (int s = 0; s < 4; ++s) {
            bf16x8 af = ldfrag(At, wm * 32 + l31, s * 2 + lh);
            bf16x8 b0 = ldfrag(Bq, wn * 32 + l31, s * 2 + lh);
            bf16x8 b1 = ldfrag(Bk, wn * 32 + l31, s * 2 + lh);
            bf16x8 b2 = ldfrag(Bv, wn * 32 + l31, s * 2 + lh);
            acc[0] = __builtin_amdgcn_mfma_f32_32x32x16_bf16(af, b0, acc[0], 0, 0, 0);
            acc[1] = __builtin_amdgcn_mfma_f32_32x32x16_bf16(af, b1, acc[1], 0, 0, 0);
            acc[2] = __builtin_amdgcn_mfma_f32_32x32x16_bf16(af, b2, acc[2], 0, 0, 0);
        }
    }
    __syncthreads();

    const int bb = row0 >> 10;
    const int head = bb * 12 + (col0 >> 6);

    // ---- z = 0 (Q, scaled) and z = 1 (K): Ct[row 0..63][col 0..63], stride 136
#pragma unroll
    for (int z = 0; z < 2; ++z) {
        const float sc = (z == 0) ? 0.125f * 1.4426950408889634f : 1.0f;
        const int ddl = wn * 32 + l31;
#pragma unroll
        for (int reg = 0; reg < 16; ++reg) {
            int rrl = wm * 32 + (reg & 3) + 8 * (reg >> 2) + 4 * lh;
            Ct[rrl * TSTRIDE + ddl] = f2bf(acc[z][reg] * sc);
        }
        __syncthreads();
        short* dst = (z == 0) ? Qg : Kg;
#pragma unroll
        for (int it = 0; it < 2; ++it) {
            int row = it * 32 + (t >> 3);
            int ck = t & 7;
            bf16x8 v = *(const bf16x8*)(Ct + row * TSTRIDE + ck * 8);
            int rr = (row0 & 1023) + row;
            *(bf16x8*)(dst + ((size_t)head * 1024 + rr) * 64 + ck * 8) = v;
        }
        __syncthreads();
    }

    // ---- z = 2 (V^T): Ct[dd 0..63][token 0..63 permuted], stride 136
    {
        const int ddl = wn * 32 + l31;
#pragma unroll
        for (int g = 0; g < 4; ++g) {
            int rrl = wm * 32 + 8 * g + 4 * lh;   // token base, %4==0, <64
            int pp = (rrl & 32) | ((rrl & 12) << 1) | ((rrl & 16) >> 2);
            short4 v4;
            v4.x = f2bf(acc[2][4 * g + 0]);
            v4.y = f2bf(acc[2][4 * g + 1]);
            v4.z = f2bf(acc[2][4 * g + 2]);
            v4.w = f2bf(acc[2][4 * g + 3]);
            *(short4*)(Ct + ddl * TSTRIDE + pp) = v4;
        }
        __syncthreads();
#pragma unroll
        for (int it = 0; it < 2; ++it) {
            int row = it * 32 + (t >> 3);   // dd 0..63
            int ck = t & 7;
            bf16x8 v = *(const bf16x8*)(Ct + row * TSTRIDE + ck * 8);
            *(bf16x8*)(Vtg + ((size_t)head * 64 + row) * 1024 + (row0 & 1023) + ck * 8) = v;
        }
    }
}

// ---------------- LSE pass (base-2, S^T, 32x32 MFMA, 128-row A tiles) ---------
// grid 768: head = b%96, r0 = (b/96)*128. Each wave owns 32 A-rows.
__global__ __launch_bounds__(256, 4) void lse_pass(
    const short* __restrict__ Aall, const short* __restrict__ Ball,
    const float* __restrict__ bias, float* __restrict__ outv,
    float bias_sign, float out_sign)
{
    __shared__ __align__(16) short At[128 * 64];
    __shared__ __align__(16) short Bt[128 * 64];
    __shared__ __align__(16) float biasl[1024];
    const int t = threadIdx.x;
    const int head = blockIdx.x % 96;
    const int r0 = (blockIdx.x / 96) * 128;
    const int lane = t & 63, w = t >> 6;
    const int l31 = lane & 31, lh = lane >> 5;
    const short* A = Aall + (size_t)head * 65536;
    const short* B = Ball + (size_t)head * 65536;

    stage_tile<4>(A + r0 * 64, 64, At, t);
    if (bias) {
        float4 v = ((const float4*)(bias + (size_t)head * 1024))[t];
        v.x *= bias_sign; v.y *= bias_sign; v.z *= bias_sign; v.w *= bias_sign;
        ((float4*)biasl)[t] = v;
    } else ((float4*)biasl)[t] = make_float4(0.f, 0.f, 0.f, 0.f);

    float lsum = 0.f;
    bf16x8 bfr[4];
    bool first = true;

    for (int j0 = 0; j0 < 1024; j0 += 128) {
        __syncthreads();
        stage_tile<4>(B + j0 * 64, 64, Bt, t);
        __syncthreads();
        if (first) {
#pragma unroll
            for (int s = 0; s < 4; ++s) bfr[s] = ldfrag(At, w * 32 + l31, s * 2 + lh);
            first = false;
        }
        f32x16 sacc[4];
#pragma unroll
        for (int mt = 0; mt < 4; ++mt)
#pragma unroll
            for (int g = 0; g < 4; ++g) {
                float4 b4 = *(const float4*)(biasl + j0 + mt * 32 + g * 8 + 4 * lh);
                sacc[mt][4 * g + 0] = b4.x; sacc[mt][4 * g + 1] = b4.y;
                sacc[mt][4 * g + 2] = b4.z; sacc[mt][4 * g + 3] = b4.w;
            }
#pragma unroll
        for (int s = 0; s < 4; ++s) {
            bf16x8 af[4];
#pragma unroll
            for (int mt = 0; mt < 4; ++mt) af[mt] = ldfrag(Bt, mt * 32 + l31, s * 2 + lh);
#pragma unroll
            for (int mt = 0; mt < 4; ++mt)
                sacc[mt] = __builtin_amdgcn_mfma_f32_32x32x16_bf16(af[mt], bfr[s], sacc[mt], 0, 0, 0);
        }
#pragma unroll
        for (int mt = 0; mt < 4; ++mt)
#pragma unroll
            for (int g = 0; g < 4; ++g) {
                float p0 = __builtin_amdgcn_exp2f(sacc[mt][4 * g + 0]);
                float p1 = __builtin_amdgcn_exp2f(sacc[mt][4 * g + 1]);
                float p2 = __builtin_amdgcn_exp2f(sacc[mt][4 * g + 2]);
                float p3 = __builtin_amdgcn_exp2f(sacc[mt][4 * g + 3]);
                lsum += (p0 + p1) + (p2 + p3);
            }
    }

    lsum += __shfl_xor(lsum, 32);
    if (lh == 0)
        outv[(size_t)head * 1024 + r0 + w * 32 + l31] =
            out_sign * __builtin_amdgcn_logf(lsum);
}

// ---------------- flash pass (16x16 MFMA, 128-row Q tiles, grid 768) ----------
// P never touches LDS (k-slot bijection); V^T pre-permuted so PV A-frag is one
// conflict-free ldfrag. v1 folded into S MFMA C-init. Q-frags hoisted.
// Row sums via ones-A-fragment MFMA. Output O^T.
__global__ __launch_bounds__(256, 4) void flash_pass(
    const short* __restrict__ Qall, const short* __restrict__ Kall,
    const short* __restrict__ Vtall, const float* __restrict__ v1,
    short* __restrict__ ctx)
{
    __shared__ __align__(16) short Qt[128 * 64];
    __shared__ __align__(16) short Kt[64 * 64];
    __shared__ __align__(16) short Vtl[64 * 64];
    __shared__ __align__(16) float v1l[1024];
    const int t = threadIdx.x;
    const int head = blockIdx.x % 96;
    const int r0 = (blockIdx.x / 96) * 128;
    const int lane = t & 63, w = t >> 6, quad = lane >> 4, c = lane & 15;
    const short* Q = Qall + (size_t)head * 65536;
    const short* K = Kall + (size_t)head * 65536;
    const short* Vt = Vtall + (size_t)head * 65536;

    stage_tile<4>(Q + r0 * 64, 64, Qt, t);
    ((float4*)v1l)[t] = ((const float4*)(v1 + (size_t)head * 1024))[t];

    f32x4 oacc[4][2];   // O^T tiles: m = d (4), n = i (2)
    f32x4 lsacc[2];     // ones^T @ P = row sums
#pragma unroll
    for (int md = 0; md < 4; ++md)
#pragma unroll
        for (int ni = 0; ni < 2; ++ni) oacc[md][ni] = (f32x4){0.f, 0.f, 0.f, 0.f};
#pragma unroll
    for (int ni = 0; ni < 2; ++ni) lsacc[ni] = (f32x4){0.f, 0.f, 0.f, 0.f};

    bf16x8 ones;
#pragma unroll
    for (int i = 0; i < 8; ++i) ones[i] = (short)0x3F80;   // bf16 1.0

    bf16x8 qfr[2][2];
    bool first = true;

    for (int j0 = 0; j0 < 1024; j0 += 64) {
        __syncthreads();
        stage_tile<2>(K + j0 * 64, 64, Kt, t);
        stage_tile<2>(Vt + j0, 1024, Vtl, t);
        __syncthreads();
        if (first) {
#pragma unroll
            for (int fn = 0; fn < 2; ++fn)
#pragma unroll
                for (int ks = 0; ks < 2; ++ks)
                    qfr[fn][ks] = ldfrag(Qt, w * 32 + fn * 16 + c, ks * 4 + quad);
            first = false;
        }
        // S^T strip with v1 bias pre-loaded into the accumulator
        f32x4 sacc[4][2];
#pragma unroll
        for (int fm = 0; fm < 4; ++fm) {
            float4 b4 = *(const float4*)(v1l + j0 + fm * 16 + quad * 4);
#pragma unroll
            for (int fn = 0; fn < 2; ++fn) sacc[fm][fn] = (f32x4){b4.x, b4.y, b4.z, b4.w};
        }
#pragma unroll
        for (int ks = 0; ks < 2; ++ks) {
            bf16x8 af[4];
#pragma unroll
            for (int fm = 0; fm < 4; ++fm) af[fm] = ldfrag(Kt, fm * 16 + c, ks * 4 + quad);
#pragma unroll
            for (int fm = 0; fm < 4; ++fm)
#pragma unroll
                for (int fn = 0; fn < 2; ++fn)
                    sacc[fm][fn] = __builtin_amdgcn_mfma_f32_16x16x32_bf16(af[fm], qfr[fn][ks], sacc[fm][fn], 0, 0, 0);
        }
        unsigned pk[4][2][2];
#pragma unroll
        for (int fm = 0; fm < 4; ++fm)
#pragma unroll
            for (int fn = 0; fn < 2; ++fn) {
                float p0 = __builtin_amdgcn_exp2f(sacc[fm][fn][0]);
                float p1 = __builtin_amdgcn_exp2f(sacc[fm][fn][1]);
                float p2 = __builtin_amdgcn_exp2f(sacc[fm][fn][2]);
                float p3 = __builtin_amdgcn_exp2f(sacc[fm][fn][3]);
                pk[fm][fn][0] = pkbf(p0, p1);
                pk[fm][fn][1] = pkbf(p2, p3);
            }
#pragma unroll
        for (int ks = 0; ks < 2; ++ks) {
            bf16x8 vaf[4];
#pragma unroll
            for (int md = 0; md < 4; ++md) vaf[md] = ldfrag(Vtl, md * 16 + c, ks * 4 + quad);
#pragma unroll
            for (int ni = 0; ni < 2; ++ni) {
                union { bf16x8 v8; unsigned u4[4]; } b;
                b.u4[0] = pk[2 * ks + 0][ni][0];
                b.u4[1] = pk[2 * ks + 0][ni][1];
                b.u4[2] = pk[2 * ks + 1][ni][0];
                b.u4[3] = pk[2 * ks + 1][ni][1];
#pragma unroll
                for (int md = 0; md < 4; ++md)
                    oacc[md][ni] = __builtin_amdgcn_mfma_f32_16x16x32_bf16(vaf[md], b.v8, oacc[md][ni], 0, 0, 0);
                lsacc[ni] = __builtin_amdgcn_mfma_f32_16x16x32_bf16(ones, b.v8, lsacc[ni], 0, 0, 0);
            }
        }
    }

    const int bb = head / 12, hh = head % 12;
#pragma unroll
    for (int ni = 0; ni < 2; ++ni) {
        float nrm = __builtin_amdgcn_rcpf(1024.f * lsacc[ni][0]);
        int rr = r0 + w * 32 + ni * 16 + c;
#pragma unroll
        for (int md = 0; md < 4; ++md) {
            short4 v4;
            v4.x = f2bf(oacc[md][ni][0] * nrm);
            v4.y = f2bf(oacc[md][ni][1] * nrm);
            v4.z = f2bf(oacc[md][ni][2] * nrm);
            v4.w = f2bf(oacc[md][ni][3] * nrm);
            *(short4*)(ctx + ((size_t)(bb * 1024 + rr)) * 768 + hh * 64 + md * 16 + quad * 4) = v4;
        }
    }
}

// ---------------- output projection (32x32x16 MFMA, 64x64 tiles) --------------
// grid (128,12) = 1536 blocks = 6/CU for balance + latency hiding.
__global__ __launch_bounds__(256, 6) void out_gemm(
    const short* __restrict__ ctxb, const short* __restrict__ wo,
    const float* __restrict__ bo, float* __restrict__ out)
{
    __shared__ __align__(16) short At[64 * 64];
    __shared__ __align__(16) short Bt[64 * 64];
    const int t = threadIdx.x;
    const int row0 = blockIdx.x * 64, col0 = blockIdx.y * 64;
    const int lane = t & 63, w = t >> 6;
    const int l31 = lane & 31, lh = lane >> 5;
    const int wm = w >> 1, wn = w & 1;

    f32x16 acc = (f32x16)(0.f);

    for (int k0 = 0; k0 < 768; k0 += 64) {
        __syncthreads();
        stage_tile<2>(ctxb + (size_t)row0 * 768 + k0, 768, At, t);
        stage_tile<2>(wo + (size_t)col0 * 768 + k0, 768, Bt, t);
        __syncthreads();
#pragma unroll
        for (int s = 0; s < 4; ++s) {
            bf16x8 af = ldfrag(At, wm * 32 + l31, s * 2 + lh);
            bf16x8 bfr = ldfrag(Bt, wn * 32 + l31, s * 2 + lh);
            acc = __builtin_amdgcn_mfma_f32_32x32x16_bf16(af, bfr, acc, 0, 0, 0);
        }
    }
    int gc = col0 + wn * 32 + l31;
    float b = bo[gc];
#pragma unroll
    for (int reg = 0; reg < 16; ++reg) {
        int gr = row0 + wm * 32 + (reg & 3) + 8 * (reg >> 2) + 4 * lh;
        out[(size_t)gr * 768 + gc] = acc[reg] + b;
    }
}

extern "C" void kernel_launch(void* const* d_in, const int* in_sizes, int n_in,
                              void* d_out, int out_size, void* d_ws, size_t ws_size,
                              hipStream_t stream) {
    const float* x  = (const float*)d_in[0];
    const float* Wq = (const float*)d_in[1];
    const float* Wk = (const float*)d_in[2];
    const float* Wv = (const float*)d_in[3];
    const float* Wo = (const float*)d_in[4];
    const float* bo = (const float*)d_in[5];
    float* out = (float*)d_out;

    char* p = (char*)d_ws;
    short* xb  = (short*)p; p += (size_t)8192 * 768 * 2;
    short* wqb = (short*)p; p += (size_t)768 * 768 * 2;
    short* wkb = (short*)p; p += (size_t)768 * 768 * 2;
    short* wvb = (short*)p; p += (size_t)768 * 768 * 2;
    short* wob = (short*)p; p += (size_t)768 * 768 * 2;
    short* Qg  = (short*)p; p += (size_t)96 * 1024 * 64 * 2;
    short* Kg  = (short*)p; p += (size_t)96 * 1024 * 64 * 2;
    short* Vtg = (short*)p; p += (size_t)96 * 1024 * 64 * 2;
    float* r1  = (float*)p; p += (size_t)96 * 1024 * 4;
    float* v1  = (float*)p; p += (size_t)96 * 1024 * 4;
    short* ctx = (short*)p; p += (size_t)8192 * 768 * 2;

    cvt_all<<<6144 + 4 * 576, 256, 0, stream>>>(x, Wq, Wk, Wv, Wo, xb, wqb, wkb, wvb, wob);

    proj_gemm<<<dim3(128, 12), 256, 0, stream>>>(xb, wqb, wkb, wvb, Qg, Kg, Vtg);

    // pass 1: r1_2[i] = +log2 sum_j exp2(S2[i,j])
    lse_pass<<<768, 256, 0, stream>>>(Qg, Kg, nullptr, r1, 0.f, 1.f);
    // pass 2: v1_2[j] = -log2 sum_i exp2(S2[i,j] - r1_2[i])
    lse_pass<<<768, 256, 0, stream>>>(Kg, Qg, r1, v1, -1.f, -1.f);

    flash_pass<<<768, 256, 0, stream>>>(Qg, Kg, Vtg, v1, ctx);

    out_gemm<<<dim3(128, 12), 256, 0, stream>>>(ctx, wob, bo, out);
}

// Round 14
// 207.397 us; speedup vs baseline: 1.0675x; 1.0675x over previous
//
#include <hip/hip_runtime.h>

#define DEV __device__ __forceinline__

typedef __attribute__((ext_vector_type(4))) float f32x4;
typedef __attribute__((ext_vector_type(16))) float f32x16;
typedef __attribute__((ext_vector_type(8))) short bf16x8;

// round-to-nearest-even f32 -> bf16 (bits in a short)
DEV short f2bf(float f) {
    union { float f; unsigned u; } v; v.f = f;
    unsigned r = (v.u + 0x7fffu + ((v.u >> 16) & 1u)) >> 16;
    return (short)r;
}

#ifndef __has_builtin
#define __has_builtin(x) 0
#endif
#if __has_builtin(__builtin_amdgcn_cvt_pk_bf16_f32)
DEV unsigned pkbf(float a, float b) {
    auto r = __builtin_amdgcn_cvt_pk_bf16_f32(a, b);
    union { __typeof__(r) v; unsigned u; } u; u.v = r; return u.u;
}
#else
DEV unsigned pkbf(float a, float b) {
    return (unsigned)(unsigned short)f2bf(a) | ((unsigned)(unsigned short)f2bf(b) << 16);
}
#endif

// async global->LDS, 16 bytes per lane. LDS dest = wave-uniform base + lane*16.
DEV void gl_lds16(const void* g, void* l) {
    __builtin_amdgcn_global_load_lds(
        (__attribute__((address_space(1))) void*)(g),
        (__attribute__((address_space(3))) void*)(l), 16, 0, 0);
}

// Stage ITERS*32 rows x 64 bf16 cols from row-major global (stride ldg shorts)
// into LDS tile with row stride 64 shorts. 16B chunks XOR-swizzled.
template <int ITERS>
DEV void stage_tile(const short* g, int ldg, short* lds, int t) {
    const int w = t >> 6;
#pragma unroll
    for (int it = 0; it < ITERS; ++it) {
        int row = it * 32 + (t >> 3);
        int cx = (t & 7) ^ ((t >> 3) & 7);
        gl_lds16(g + row * ldg + cx * 8, (char*)lds + it * 4096 + (w << 10));
    }
}

// read 8-bf16 fragment: chunk kc (0..7) of tile row r (row stride 64 shorts)
DEV bf16x8 ldfrag(const short* lds, int r, int kc) {
    return *(const bf16x8*)(lds + r * 64 + ((kc ^ (r & 7)) << 3));
}

// ---------------- conversion (all 5 tensors in one launch) ----------------
__global__ void cvt_all(const float* __restrict__ x,
                        const float* __restrict__ wq, const float* __restrict__ wk,
                        const float* __restrict__ wv, const float* __restrict__ wo,
                        short* __restrict__ xb,
                        short* __restrict__ wqb, short* __restrict__ wkb,
                        short* __restrict__ wvb, short* __restrict__ wob) {
    int b = blockIdx.x;
    const float* s; short* d; int i;
    if (b < 6144) {
        s = x; d = xb; i = b * 256 + threadIdx.x;
    } else {
        int r = b - 6144;
        int wi = r / 576, rem = r - wi * 576;
        s = (wi == 0) ? wq : (wi == 1) ? wk : (wi == 2) ? wv : wo;
        d = (wi == 0) ? wqb : (wi == 1) ? wkb : (wi == 2) ? wvb : wob;
        i = rem * 256 + threadIdx.x;
    }
    float4 v = ((const float4*)s)[i];
    short4 o;
    o.x = f2bf(v.x); o.y = f2bf(v.y); o.z = f2bf(v.z); o.w = f2bf(v.w);
    ((short4*)d)[i] = o;
}

// ---------------- fused QKV projection (32x32x16 MFMA, z-fused, R12 form) -----
// One block = 128-row x 64-col tile for ALL THREE outputs: x-tile staged once.
// Q gets scale (1/8)*log2(e) folded. V^T stored with token columns PERMUTED
// within each 64-group: n = (j&32)|((j&12)<<1)|((j&16)>>2)|(j&3) — matches
// flash's 16x16 PV k-slot bijection (PV A-frag = one conflict-free ldfrag).
#define TSTRIDE 136
__global__ __launch_bounds__(256, 3) void proj_gemm(
    const short* __restrict__ xb,
    const short* __restrict__ wq, const short* __restrict__ wk, const short* __restrict__ wv,
    short* __restrict__ Qg, short* __restrict__ Kg, short* __restrict__ Vtg)
{
    __shared__ __align__(16) char smem[40960];
    short* const At = (short*)smem;                 // 128x64 = 16 KB
    short* const Bq = (short*)(smem + 16384);       // 64x64 = 8 KB
    short* const Bk = (short*)(smem + 24576);
    short* const Bv = (short*)(smem + 32768);
    short* const Ct = (short*)smem;                 // epilogue overlay
    const int t = threadIdx.x;
    const int row0 = blockIdx.x * 128, col0 = blockIdx.y * 64;
    const int lane = t & 63, w = t >> 6;
    const int l31 = lane & 31, lh = lane >> 5;
    const int wm = w >> 1, wn = w & 1;

    f32x16 acc[3][2];
#pragma unroll
    for (int z = 0; z < 3; ++z)
#pragma unroll
        for (int tm = 0; tm < 2; ++tm) acc[z][tm] = (f32x16)(0.f);

    const short* Asrc = xb + (size_t)row0 * 768;
    const short* Qs = wq + (size_t)col0 * 768;
    const short* Ks = wk + (size_t)col0 * 768;
    const short* Vs = wv + (size_t)col0 * 768;

    for (int k = 0; k < 12; ++k) {
        __syncthreads();
        stage_tile<4>(Asrc + k * 64, 768, At, t);
        stage_tile<2>(Qs + k * 64, 768, Bq, t);
        stage_tile<2>(Ks + k * 64, 768, Bk, t);
        stage_tile<2>(Vs + k * 64, 768, Bv, t);
        __syncthreads();
#pragma unroll
        for (int s = 0; s < 4; ++s) {
            bf16x8 af[2];
#pragma unroll
            for (int tm = 0; tm < 2; ++tm) af[tm] = ldfrag(At, wm * 64 + tm * 32 + l31, s * 2 + lh);
            bf16x8 b0 = ldfrag(Bq, wn * 32 + l31, s * 2 + lh);
            bf16x8 b1 = ldfrag(Bk, wn * 32 + l31, s * 2 + lh);
            bf16x8 b2 = ldfrag(Bv, wn * 32 + l31, s * 2 + lh);
#pragma unroll
            for (int tm = 0; tm < 2; ++tm) {
                acc[0][tm] = __builtin_amdgcn_mfma_f32_32x32x16_bf16(af[tm], b0, acc[0][tm], 0, 0, 0);
                acc[1][tm] = __builtin_amdgcn_mfma_f32_32x32x16_bf16(af[tm], b1, acc[1][tm], 0, 0, 0);
                acc[2][tm] = __builtin_amdgcn_mfma_f32_32x32x16_bf16(af[tm], b2, acc[2][tm], 0, 0, 0);
            }
        }
    }
    __syncthreads();

    const int bb = row0 >> 10;
    const int head = bb * 12 + (col0 >> 6);

    // ---- z = 0 (Q, scaled) and z = 1 (K): Ct[row 0..127][col 0..63], stride 136
#pragma unroll
    for (int z = 0; z < 2; ++z) {
        const float sc = (z == 0) ? 0.125f * 1.4426950408889634f : 1.0f;
        const int ddl = wn * 32 + l31;
#pragma unroll
        for (int tm = 0; tm < 2; ++tm)
#pragma unroll
            for (int reg = 0; reg < 16; ++reg) {
                int rrl = wm * 64 + tm * 32 + (reg & 3) + 8 * (reg >> 2) + 4 * lh;
                Ct[rrl * TSTRIDE + ddl] = f2bf(acc[z][tm][reg] * sc);
            }
        __syncthreads();
        short* dst = (z == 0) ? Qg : Kg;
#pragma unroll
        for (int it = 0; it < 4; ++it) {
            int row = it * 32 + (t >> 3);
            int ck = t & 7;
            bf16x8 v = *(const bf16x8*)(Ct + row * TSTRIDE + ck * 8);
            int rr = (row0 & 1023) + row;
            *(bf16x8*)(dst + ((size_t)head * 1024 + rr) * 64 + ck * 8) = v;
        }
        __syncthreads();
    }

    // ---- z = 2 (V^T): Ct[dd 0..63][token 0..127 permuted], stride 136
    {
        const int ddl = wn * 32 + l31;
#pragma unroll
        for (int tm = 0; tm < 2; ++tm)
#pragma unroll
            for (int g = 0; g < 4; ++g) {
                int rrl = wm * 64 + tm * 32 + 8 * g + 4 * lh;   // token base, %4==0
                int j6 = rrl & 63;
                int pp = (rrl & ~63) | (j6 & 32) | ((j6 & 12) << 1) | ((j6 & 16) >> 2);
                short4 v4;
                v4.x = f2bf(acc[2][tm][4 * g + 0]);
                v4.y = f2bf(acc[2][tm][4 * g + 1]);
                v4.z = f2bf(acc[2][tm][4 * g + 2]);
                v4.w = f2bf(acc[2][tm][4 * g + 3]);
                *(short4*)(Ct + ddl * TSTRIDE + pp) = v4;
            }
        __syncthreads();
#pragma unroll
        for (int it = 0; it < 4; ++it) {
            int row = it * 16 + (t >> 4);   // dd 0..63
            int ck = t & 15;
            bf16x8 v = *(const bf16x8*)(Ct + row * TSTRIDE + ck * 8);
            *(bf16x8*)(Vtg + ((size_t)head * 64 + row) * 1024 + (row0 & 1023) + ck * 8) = v;
        }
    }
}

// ---------------- LSE pass (base-2, S^T, 32x32 MFMA, 128-row A tiles) ---------
// grid 768: head = b%96, r0 = (b/96)*128. Each wave owns 32 A-rows.
__global__ __launch_bounds__(256, 4) void lse_pass(
    const short* __restrict__ Aall, const short* __restrict__ Ball,
    const float* __restrict__ bias, float* __restrict__ outv,
    float bias_sign, float out_sign)
{
    __shared__ __align__(16) short At[128 * 64];
    __shared__ __align__(16) short Bt[128 * 64];
    __shared__ __align__(16) float biasl[1024];
    const int t = threadIdx.x;
    const int head = blockIdx.x % 96;
    const int r0 = (blockIdx.x / 96) * 128;
    const int lane = t & 63, w = t >> 6;
    const int l31 = lane & 31, lh = lane >> 5;
    const short* A = Aall + (size_t)head * 65536;
    const short* B = Ball + (size_t)head * 65536;

    stage_tile<4>(A + r0 * 64, 64, At, t);
    if (bias) {
        float4 v = ((const float4*)(bias + (size_t)head * 1024))[t];
        v.x *= bias_sign; v.y *= bias_sign; v.z *= bias_sign; v.w *= bias_sign;
        ((float4*)biasl)[t] = v;
    } else ((float4*)biasl)[t] = make_float4(0.f, 0.f, 0.f, 0.f);

    float lsum = 0.f;
    bf16x8 bfr[4];
    bool first = true;

    for (int j0 = 0; j0 < 1024; j0 += 128) {
        __syncthreads();
        stage_tile<4>(B + j0 * 64, 64, Bt, t);
        __syncthreads();
        if (first) {
#pragma unroll
            for (int s = 0; s < 4; ++s) bfr[s] = ldfrag(At, w * 32 + l31, s * 2 + lh);
            first = false;
        }
        f32x16 sacc[4];
#pragma unroll
        for (int mt = 0; mt < 4; ++mt)
#pragma unroll
            for (int g = 0; g < 4; ++g) {
                float4 b4 = *(const float4*)(biasl + j0 + mt * 32 + g * 8 + 4 * lh);
                sacc[mt][4 * g + 0] = b4.x; sacc[mt][4 * g + 1] = b4.y;
                sacc[mt][4 * g + 2] = b4.z; sacc[mt][4 * g + 3] = b4.w;
            }
#pragma unroll
        for (int s = 0; s < 4; ++s) {
            bf16x8 af[4];
#pragma unroll
            for (int mt = 0; mt < 4; ++mt) af[mt] = ldfrag(Bt, mt * 32 + l31, s * 2 + lh);
#pragma unroll
            for (int mt = 0; mt < 4; ++mt)
                sacc[mt] = __builtin_amdgcn_mfma_f32_32x32x16_bf16(af[mt], bfr[s], sacc[mt], 0, 0, 0);
        }
#pragma unroll
        for (int mt = 0; mt < 4; ++mt)
#pragma unroll
            for (int g = 0; g < 4; ++g) {
                float p0 = __builtin_amdgcn_exp2f(sacc[mt][4 * g + 0]);
                float p1 = __builtin_amdgcn_exp2f(sacc[mt][4 * g + 1]);
                float p2 = __builtin_amdgcn_exp2f(sacc[mt][4 * g + 2]);
                float p3 = __builtin_amdgcn_exp2f(sacc[mt][4 * g + 3]);
                lsum += (p0 + p1) + (p2 + p3);
            }
    }

    lsum += __shfl_xor(lsum, 32);
    if (lh == 0)
        outv[(size_t)head * 1024 + r0 + w * 32 + l31] =
            out_sign * __builtin_amdgcn_logf(lsum);
}

// ---------------- flash pass (16x16 MFMA, 128-row Q, 128-col j-tiles) ---------
// P never touches LDS (k-slot bijection); V^T pre-permuted so PV A-frag is one
// conflict-free ldfrag. v1 folded into S MFMA C-init. Q-frags hoisted.
// Row sums via ones-A-fragment MFMA. j-tile 128 (two 64-wide sub-tiles per
// barrier pair) halves barrier count. Output O^T.
__global__ __launch_bounds__(256, 3) void flash_pass(
    const short* __restrict__ Qall, const short* __restrict__ Kall,
    const short* __restrict__ Vtall, const float* __restrict__ v1,
    short* __restrict__ ctx)
{
    __shared__ __align__(16) short Qt[128 * 64];
    __shared__ __align__(16) short Kt[2 * 64 * 64];
    __shared__ __align__(16) short Vtl[2 * 64 * 64];
    __shared__ __align__(16) float v1l[1024];
    const int t = threadIdx.x;
    const int head = blockIdx.x % 96;
    const int r0 = (blockIdx.x / 96) * 128;
    const int lane = t & 63, w = t >> 6, quad = lane >> 4, c = lane & 15;
    const short* Q = Qall + (size_t)head * 65536;
    const short* K = Kall + (size_t)head * 65536;
    const short* Vt = Vtall + (size_t)head * 65536;

    stage_tile<4>(Q + r0 * 64, 64, Qt, t);
    ((float4*)v1l)[t] = ((const float4*)(v1 + (size_t)head * 1024))[t];

    f32x4 oacc[4][2];   // O^T tiles: m = d (4), n = i (2)
    f32x4 lsacc[2];     // ones^T @ P = row sums
#pragma unroll
    for (int md = 0; md < 4; ++md)
#pragma unroll
        for (int ni = 0; ni < 2; ++ni) oacc[md][ni] = (f32x4){0.f, 0.f, 0.f, 0.f};
#pragma unroll
    for (int ni = 0; ni < 2; ++ni) lsacc[ni] = (f32x4){0.f, 0.f, 0.f, 0.f};

    bf16x8 ones;
#pragma unroll
    for (int i = 0; i < 8; ++i) ones[i] = (short)0x3F80;   // bf16 1.0

    bf16x8 qfr[2][2];
    bool first = true;

    for (int jb = 0; jb < 1024; jb += 128) {
        __syncthreads();
        stage_tile<2>(K + jb * 64, 64, Kt, t);
        stage_tile<2>(K + (jb + 64) * 64, 64, Kt + 4096, t);
        stage_tile<2>(Vt + jb, 1024, Vtl, t);
        stage_tile<2>(Vt + jb + 64, 1024, Vtl + 4096, t);
        __syncthreads();
        if (first) {
#pragma unroll
            for (int fn = 0; fn < 2; ++fn)
#pragma unroll
                for (int ks = 0; ks < 2; ++ks)
                    qfr[fn][ks] = ldfrag(Qt, w * 32 + fn * 16 + c, ks * 4 + quad);
            first = false;
        }
#pragma unroll
        for (int half = 0; half < 2; ++half) {
            const short* Kth = Kt + half * 4096;
            const short* Vth = Vtl + half * 4096;
            const int j0 = jb + half * 64;
            // S^T strip with v1 bias pre-loaded into the accumulator
            f32x4 sacc[4][2];
#pragma unroll
            for (int fm = 0; fm < 4; ++fm) {
                float4 b4 = *(const float4*)(v1l + j0 + fm * 16 + quad * 4);
#pragma unroll
                for (int fn = 0; fn < 2; ++fn) sacc[fm][fn] = (f32x4){b4.x, b4.y, b4.z, b4.w};
            }
#pragma unroll
            for (int ks = 0; ks < 2; ++ks) {
                bf16x8 af[4];
#pragma unroll
                for (int fm = 0; fm < 4; ++fm) af[fm] = ldfrag(Kth, fm * 16 + c, ks * 4 + quad);
#pragma unroll
                for (int fm = 0; fm < 4; ++fm)
#pragma unroll
                    for (int fn = 0; fn < 2; ++fn)
                        sacc[fm][fn] = __builtin_amdgcn_mfma_f32_16x16x32_bf16(af[fm], qfr[fn][ks], sacc[fm][fn], 0, 0, 0);
            }
            unsigned pk[4][2][2];
#pragma unroll
            for (int fm = 0; fm < 4; ++fm)
#pragma unroll
                for (int fn = 0; fn < 2; ++fn) {
                    float p0 = __builtin_amdgcn_exp2f(sacc[fm][fn][0]);
                    float p1 = __builtin_amdgcn_exp2f(sacc[fm][fn][1]);
                    float p2 = __builtin_amdgcn_exp2f(sacc[fm][fn][2]);
                    float p3 = __builtin_amdgcn_exp2f(sacc[fm][fn][3]);
                    pk[fm][fn][0] = pkbf(p0, p1);
                    pk[fm][fn][1] = pkbf(p2, p3);
                }
#pragma unroll
            for (int ks = 0; ks < 2; ++ks) {
                bf16x8 vaf[4];
#pragma unroll
                for (int md = 0; md < 4; ++md) vaf[md] = ldfrag(Vth, md * 16 + c, ks * 4 + quad);
#pragma unroll
                for (int ni = 0; ni < 2; ++ni) {
                    union { bf16x8 v8; unsigned u4[4]; } b;
                    b.u4[0] = pk[2 * ks + 0][ni][0];
                    b.u4[1] = pk[2 * ks + 0][ni][1];
                    b.u4[2] = pk[2 * ks + 1][ni][0];
                    b.u4[3] = pk[2 * ks + 1][ni][1];
#pragma unroll
                    for (int md = 0; md < 4; ++md)
                        oacc[md][ni] = __builtin_amdgcn_mfma_f32_16x16x32_bf16(vaf[md], b.v8, oacc[md][ni], 0, 0, 0);
                    lsacc[ni] = __builtin_amdgcn_mfma_f32_16x16x32_bf16(ones, b.v8, lsacc[ni], 0, 0, 0);
                }
            }
        }
    }

    const int bb = head / 12, hh = head % 12;
#pragma unroll
    for (int ni = 0; ni < 2; ++ni) {
        float nrm = __builtin_amdgcn_rcpf(1024.f * lsacc[ni][0]);
        int rr = r0 + w * 32 + ni * 16 + c;
#pragma unroll
        for (int md = 0; md < 4; ++md) {
            short4 v4;
            v4.x = f2bf(oacc[md][ni][0] * nrm);
            v4.y = f2bf(oacc[md][ni][1] * nrm);
            v4.z = f2bf(oacc[md][ni][2] * nrm);
            v4.w = f2bf(oacc[md][ni][3] * nrm);
            *(short4*)(ctx + ((size_t)(bb * 1024 + rr)) * 768 + hh * 64 + md * 16 + quad * 4) = v4;
        }
    }
}

// ---------------- output projection (32x32x16 MFMA, R12 form) -----------------
__global__ __launch_bounds__(256, 4) void out_gemm(
    const short* __restrict__ ctxb, const short* __restrict__ wo,
    const float* __restrict__ bo, float* __restrict__ out)
{
    __shared__ __align__(16) short At[128 * 64];
    __shared__ __align__(16) short Bt[128 * 64];
    const int t = threadIdx.x;
    const int row0 = blockIdx.x * 128, col0 = blockIdx.y * 128;
    const int lane = t & 63, w = t >> 6;
    const int l31 = lane & 31, lh = lane >> 5;
    const int wm = w >> 1, wn = w & 1;

    f32x16 acc[2][2];
#pragma unroll
    for (int i = 0; i < 2; ++i)
#pragma unroll
        for (int j = 0; j < 2; ++j) acc[i][j] = (f32x16)(0.f);

    for (int k0 = 0; k0 < 768; k0 += 64) {
        __syncthreads();
        stage_tile<4>(ctxb + (size_t)row0 * 768 + k0, 768, At, t);
        stage_tile<4>(wo + (size_t)col0 * 768 + k0, 768, Bt, t);
        __syncthreads();
#pragma unroll
        for (int s = 0; s < 4; ++s) {
            bf16x8 af[2], bfr[2];
#pragma unroll
            for (int tm = 0; tm < 2; ++tm) af[tm] = ldfrag(At, wm * 64 + tm * 32 + l31, s * 2 + lh);
#pragma unroll
            for (int tn = 0; tn < 2; ++tn) bfr[tn] = ldfrag(Bt, wn * 64 + tn * 32 + l31, s * 2 + lh);
#pragma unroll
            for (int tm = 0; tm < 2; ++tm)
#pragma unroll
                for (int tn = 0; tn < 2; ++tn)
                    acc[tm][tn] = __builtin_amdgcn_mfma_f32_32x32x16_bf16(af[tm], bfr[tn], acc[tm][tn], 0, 0, 0);
        }
    }
#pragma unroll
    for (int tm = 0; tm < 2; ++tm)
#pragma unroll
        for (int tn = 0; tn < 2; ++tn) {
            int gc = col0 + wn * 64 + tn * 32 + l31;
            float b = bo[gc];
#pragma unroll
            for (int reg = 0; reg < 16; ++reg) {
                int gr = row0 + wm * 64 + tm * 32 + (reg & 3) + 8 * (reg >> 2) + 4 * lh;
                out[(size_t)gr * 768 + gc] = acc[tm][tn][reg] + b;
            }
        }
}

extern "C" void kernel_launch(void* const* d_in, const int* in_sizes, int n_in,
                              void* d_out, int out_size, void* d_ws, size_t ws_size,
                              hipStream_t stream) {
    const float* x  = (const float*)d_in[0];
    const float* Wq = (const float*)d_in[1];
    const float* Wk = (const float*)d_in[2];
    const float* Wv = (const float*)d_in[3];
    const float* Wo = (const float*)d_in[4];
    const float* bo = (const float*)d_in[5];
    float* out = (float*)d_out;

    char* p = (char*)d_ws;
    short* xb  = (short*)p; p += (size_t)8192 * 768 * 2;
    short* wqb = (short*)p; p += (size_t)768 * 768 * 2;
    short* wkb = (short*)p; p += (size_t)768 * 768 * 2;
    short* wvb = (short*)p; p += (size_t)768 * 768 * 2;
    short* wob = (short*)p; p += (size_t)768 * 768 * 2;
    short* Qg  = (short*)p; p += (size_t)96 * 1024 * 64 * 2;
    short* Kg  = (short*)p; p += (size_t)96 * 1024 * 64 * 2;
    short* Vtg = (short*)p; p += (size_t)96 * 1024 * 64 * 2;
    float* r1  = (float*)p; p += (size_t)96 * 1024 * 4;
    float* v1  = (float*)p; p += (size_t)96 * 1024 * 4;
    short* ctx = (short*)p; p += (size_t)8192 * 768 * 2;

    cvt_all<<<6144 + 4 * 576, 256, 0, stream>>>(x, Wq, Wk, Wv, Wo, xb, wqb, wkb, wvb, wob);

    proj_gemm<<<dim3(64, 12), 256, 0, stream>>>(xb, wqb, wkb, wvb, Qg, Kg, Vtg);

    // pass 1: r1_2[i] = +log2 sum_j exp2(S2[i,j])
    lse_pass<<<768, 256, 0, stream>>>(Qg, Kg, nullptr, r1, 0.f, 1.f);
    // pass 2: v1_2[j] = -log2 sum_i exp2(S2[i,j] - r1_2[i])
    lse_pass<<<768, 256, 0, stream>>>(Kg, Qg, r1, v1, -1.f, -1.f);

    flash_pass<<<768, 256, 0, stream>>>(Qg, Kg, Vtg, v1, ctx);

    out_gemm<<<dim3(64, 6), 256, 0, stream>>>(ctx, wob, bo, out);
}